// Round 2
// baseline (249.769 us; speedup 1.0000x reference)
//
#include <hip/hip_runtime.h>
#include <hip/hip_bf16.h>
#include <math.h>

// Problem constants (fixed by setup_inputs: B=8, M=1024, D=256, H=W=100)
#define BATCH 8
#define MQ    1024
#define DIM   256
#define NHEAD 8
#define NPTS  4
#define NPROJ 98            // 64 offsets + 32 attn logits + 2 base-ref

// ---------------------------------------------------------------------------
// Kernel A: fused projections + softmax + bilinear sample + weighted agg.
// One block per (b, m) row. 256 threads = one channel each.
// Writes agg[row][d] (fp32) into workspace.
// ---------------------------------------------------------------------------
__global__ __launch_bounds__(256) void fused_sample_kernel(
    const float* __restrict__ SADQ,   // [B, M, D]
    const float* __restrict__ E,      // [B, H*W, D]
    const float* __restrict__ Wo, const float* __restrict__ bo,   // [D,64],[64]
    const float* __restrict__ Wa, const float* __restrict__ ba,   // [D,32],[32]
    const float* __restrict__ Wr, const float* __restrict__ br,   // [D,2],[2]
    const int*   __restrict__ Hp, const int* __restrict__ Wdp,    // scalars
    float* __restrict__ agg)          // [B*M, D]
{
    const int row = blockIdx.x;       // b*MQ + m
    const int b   = row / MQ;
    const int tid = threadIdx.x;

    __shared__ float qs[DIM];
    __shared__ float proj[128];       // [0,64) offsets, [64,96) logits, [96,98) base
    __shared__ float partial[128];    // upper-half d partial sums
    __shared__ float sW[NHEAD * NPTS * 4];
    __shared__ int   sIdx[NHEAD * NPTS * 4];

    qs[tid] = SADQ[(size_t)row * DIM + tid];
    __syncthreads();

    // ---- Phase 1: projections. Output j computed by two threads (d halves).
    {
        const int j    = tid & 127;
        const int half = tid >> 7;
        float s = 0.f, bias = 0.f;
        if (j < NPROJ) {
            const float* Wb; int col, ncols;
            if (j < 64)      { Wb = Wo; col = j;      ncols = 64; bias = bo[col]; }
            else if (j < 96) { Wb = Wa; col = j - 64; ncols = 32; bias = ba[col]; }
            else             { Wb = Wr; col = j - 96; ncols = 2;  bias = br[col]; }
            const float* wp = Wb + (size_t)(half * 128) * ncols + col;
            const float* qp = qs + half * 128;
            #pragma unroll 8
            for (int d = 0; d < 128; ++d)
                s = fmaf(qp[d], wp[(size_t)d * ncols], s);
        }
        if (half) partial[j] = s;
        __syncthreads();
        if (!half && j < NPROJ) proj[j] = s + bias + partial[j];
        __syncthreads();
    }

    // ---- Phase 2: softmax over each head's 4 points + per-point corner setup.
    const int Hh = *Hp;
    const int Ww = *Wdp;
    if (tid < NHEAD * NPTS) {
        const int p = tid;            // linear (h*4 + pt)
        const int h = p >> 2;
        const float l0 = proj[64 + h * 4 + 0];
        const float l1 = proj[64 + h * 4 + 1];
        const float l2 = proj[64 + h * 4 + 2];
        const float l3 = proj[64 + h * 4 + 3];
        const float mx = fmaxf(fmaxf(l0, l1), fmaxf(l2, l3));
        const float e0 = expf(l0 - mx), e1 = expf(l1 - mx),
                    e2 = expf(l2 - mx), e3 = expf(l3 - mx);
        const float inv = 1.f / (e0 + e1 + e2 + e3);
        const float aw  = expf(proj[64 + p] - mx) * inv * (1.f / NHEAD);

        const float lx = proj[96] + 0.1f * proj[p * 2 + 0];
        const float ly = proj[97] + 0.1f * proj[p * 2 + 1];
        const float ix = ((lx + 1.f) * (float)Ww - 1.f) * 0.5f;
        const float iy = ((ly + 1.f) * (float)Hh - 1.f) * 0.5f;
        const float x0f = floorf(ix), y0f = floorf(iy);
        const int   x0  = (int)x0f,   y0  = (int)y0f;
        const float wx1 = ix - x0f, wx0 = 1.f - wx1;
        const float wy1 = iy - y0f, wy0 = 1.f - wy1;

        #pragma unroll
        for (int c = 0; c < 4; ++c) {
            const int   xc = x0 + (c & 1);
            const int   yc = y0 + (c >> 1);
            const float wx = (c & 1) ? wx1 : wx0;
            const float wy = (c >> 1) ? wy1 : wy0;
            const bool valid = (xc >= 0) && (xc < Ww) && (yc >= 0) && (yc < Hh);
            const int xi = min(max(xc, 0), Ww - 1);
            const int yi = min(max(yc, 0), Hh - 1);
            sW  [p * 4 + c] = valid ? (wx * wy * aw) : 0.f;
            sIdx[p * 4 + c] = (yi * Ww + xi) * DIM;
        }
    }
    __syncthreads();

    // ---- Phase 3: gather + weighted accumulate (channel = tid).
    const float* __restrict__ Eb = E + (size_t)b * (size_t)(Hh * Ww) * DIM;
    float acc = 0.f;
    #pragma unroll 4
    for (int i = 0; i < NHEAD * NPTS * 4; ++i) {
        const float w   = sW[i];
        const int   idx = sIdx[i];
        acc = fmaf(w, Eb[idx + tid], acc);
    }
    agg[(size_t)row * DIM + tid] = acc;
}

// ---------------------------------------------------------------------------
// Kernel B: out = agg @ Wp + bp.  [8192,256] x [256,256], fp32 vector FMA.
// 64x64 tile per block, BK=16, 256 threads, 4x4 micro-tile per thread.
// ---------------------------------------------------------------------------
__global__ __launch_bounds__(256) void proj_gemm_kernel(
    const float* __restrict__ A,      // [BM, 256]
    const float* __restrict__ Wp,     // [256, 256]
    const float* __restrict__ bp,     // [256]
    float* __restrict__ out)          // [BM, 256]
{
    __shared__ float As[16][64];      // transposed A tile: As[k][m]
    __shared__ float Bs[16][64];      // Bs[k][n]

    const int tid = threadIdx.x;
    const int mb  = blockIdx.x * 64;
    const int nb  = blockIdx.y * 64;
    const int tm  = (tid >> 4) << 2;  // row offset in tile
    const int tn  = (tid & 15) << 2;  // col offset in tile

    float acc[4][4] = {};

    for (int kb = 0; kb < DIM; kb += 16) {
        // Stage A (transposed) — each thread: one float4 along k.
        {
            const int m  = tid & 63;
            const int k0 = (tid >> 6) << 2;
            const float4 v = *(const float4*)&A[(size_t)(mb + m) * DIM + kb + k0];
            As[k0 + 0][m] = v.x; As[k0 + 1][m] = v.y;
            As[k0 + 2][m] = v.z; As[k0 + 3][m] = v.w;
            // Stage B — coalesced row-major float4.
            const int k = tid >> 4;
            const int n = (tid & 15) << 2;
            *(float4*)&Bs[k][n] = *(const float4*)&Wp[(size_t)(kb + k) * DIM + nb + n];
        }
        __syncthreads();

        #pragma unroll
        for (int k = 0; k < 16; ++k) {
            const float4 a  = *(const float4*)&As[k][tm];
            const float4 b4 = *(const float4*)&Bs[k][tn];
            acc[0][0] = fmaf(a.x, b4.x, acc[0][0]);
            acc[0][1] = fmaf(a.x, b4.y, acc[0][1]);
            acc[0][2] = fmaf(a.x, b4.z, acc[0][2]);
            acc[0][3] = fmaf(a.x, b4.w, acc[0][3]);
            acc[1][0] = fmaf(a.y, b4.x, acc[1][0]);
            acc[1][1] = fmaf(a.y, b4.y, acc[1][1]);
            acc[1][2] = fmaf(a.y, b4.z, acc[1][2]);
            acc[1][3] = fmaf(a.y, b4.w, acc[1][3]);
            acc[2][0] = fmaf(a.z, b4.x, acc[2][0]);
            acc[2][1] = fmaf(a.z, b4.y, acc[2][1]);
            acc[2][2] = fmaf(a.z, b4.z, acc[2][2]);
            acc[2][3] = fmaf(a.z, b4.w, acc[2][3]);
            acc[3][0] = fmaf(a.w, b4.x, acc[3][0]);
            acc[3][1] = fmaf(a.w, b4.y, acc[3][1]);
            acc[3][2] = fmaf(a.w, b4.z, acc[3][2]);
            acc[3][3] = fmaf(a.w, b4.w, acc[3][3]);
        }
        __syncthreads();
    }

    const float4 bv = *(const float4*)&bp[nb + tn];
    #pragma unroll
    for (int i = 0; i < 4; ++i) {
        float4 o;
        o.x = acc[i][0] + bv.x;
        o.y = acc[i][1] + bv.y;
        o.z = acc[i][2] + bv.z;
        o.w = acc[i][3] + bv.w;
        *(float4*)&out[(size_t)(mb + tm + i) * DIM + nb + tn] = o;
    }
}

// ---------------------------------------------------------------------------
extern "C" void kernel_launch(void* const* d_in, const int* in_sizes, int n_in,
                              void* d_out, int out_size, void* d_ws, size_t ws_size,
                              hipStream_t stream)
{
    const float* SADQ = (const float*)d_in[0];
    const float* E    = (const float*)d_in[1];
    const float* Wo   = (const float*)d_in[2];
    const float* bo   = (const float*)d_in[3];
    const float* Wa   = (const float*)d_in[4];
    const float* ba   = (const float*)d_in[5];
    const float* Wr   = (const float*)d_in[6];
    const float* br   = (const float*)d_in[7];
    const float* Wp   = (const float*)d_in[8];
    const float* bp   = (const float*)d_in[9];
    const int*   Hp   = (const int*)d_in[10];
    const int*   Wdp  = (const int*)d_in[11];

    float* agg = (float*)d_ws;                 // [B*M, D] fp32 = 8 MB
    float* out = (float*)d_out;

    const int BM = in_sizes[0] / DIM;          // 8192 rows

    fused_sample_kernel<<<BM, 256, 0, stream>>>(
        SADQ, E, Wo, bo, Wa, ba, Wr, br, Hp, Wdp, agg);

    dim3 g2(BM / 64, DIM / 64);
    proj_gemm_kernel<<<g2, 256, 0, stream>>>(agg, Wp, bp, out);
}

// Round 4
// 229.542 us; speedup vs baseline: 1.0881x; 1.0881x over previous
//
#include <hip/hip_runtime.h>
#include <hip/hip_bf16.h>
#include <math.h>

// Problem constants (fixed by setup_inputs: B=8, M=1024, D=256, H=W=100)
#define BATCH 8
#define MQ    1024
#define DIM   256
#define NHEAD 8
#define NPTS  4
#define NPROJ 98            // 64 offsets + 32 attn logits + 2 base-ref
#define NCORN (NHEAD * NPTS * 4)   // 128 corner samples per row

// ---------------------------------------------------------------------------
// Kernel A: fused projections + softmax + bilinear sample + weighted agg.
// One block per (b, m) row. 256 threads = 4 corner-groups x 64 float4 lanes.
// Phase 3 is the hot part: 32 independent float4 gathers in flight per thread.
// ---------------------------------------------------------------------------
__global__ __launch_bounds__(256) void fused_sample_kernel(
    const float* __restrict__ SADQ,   // [B, M, D]
    const float* __restrict__ E,      // [B, H*W, D]
    const float* __restrict__ Wo, const float* __restrict__ bo,   // [D,64],[64]
    const float* __restrict__ Wa, const float* __restrict__ ba,   // [D,32],[32]
    const float* __restrict__ Wr, const float* __restrict__ br,   // [D,2],[2]
    const int*   __restrict__ Hp, const int* __restrict__ Wdp,    // scalars
    float* __restrict__ agg)          // [B*M, D]
{
    const int row = blockIdx.x;       // b*MQ + m
    const int b   = row / MQ;
    const int tid = threadIdx.x;

    __shared__ float  qs[DIM];
    __shared__ float  proj[128];      // [0,64) offsets, [64,96) logits, [96,98) base
    __shared__ float  partial[128];   // upper-half d partial sums
    __shared__ float  sW[NCORN];
    __shared__ int    sIdx[NCORN];    // pixel index in float4 units (pix*64)
    __shared__ float4 red[4][64];     // cross-corner-group reduction

    qs[tid] = SADQ[(size_t)row * DIM + tid];
    __syncthreads();

    // ---- Phase 1: projections. Output j computed by two threads (d halves).
    {
        const int j    = tid & 127;
        const int half = tid >> 7;
        float s = 0.f, bias = 0.f;
        if (j < NPROJ) {
            const float* Wb; int col, ncols;
            if (j < 64)      { Wb = Wo; col = j;      ncols = 64; bias = bo[col]; }
            else if (j < 96) { Wb = Wa; col = j - 64; ncols = 32; bias = ba[col]; }
            else             { Wb = Wr; col = j - 96; ncols = 2;  bias = br[col]; }
            const float* wp = Wb + (size_t)(half * 128) * ncols + col;
            const float* qp = qs + half * 128;
            #pragma unroll 8
            for (int d = 0; d < 128; ++d)
                s = fmaf(qp[d], wp[(size_t)d * ncols], s);
        }
        if (half) partial[j] = s;
        __syncthreads();
        if (!half && j < NPROJ) proj[j] = s + bias + partial[j];
        __syncthreads();
    }

    // ---- Phase 2: softmax over each head's 4 points + per-point corner setup.
    const int Hh = *Hp;
    const int Ww = *Wdp;
    if (tid < NHEAD * NPTS) {
        const int p = tid;            // linear (h*4 + pt)
        const int h = p >> 2;
        const float l0 = proj[64 + h * 4 + 0];
        const float l1 = proj[64 + h * 4 + 1];
        const float l2 = proj[64 + h * 4 + 2];
        const float l3 = proj[64 + h * 4 + 3];
        const float mx = fmaxf(fmaxf(l0, l1), fmaxf(l2, l3));
        const float e0 = expf(l0 - mx), e1 = expf(l1 - mx),
                    e2 = expf(l2 - mx), e3 = expf(l3 - mx);
        const float inv = 1.f / (e0 + e1 + e2 + e3);
        const float aw  = expf(proj[64 + p] - mx) * inv * (1.f / NHEAD);

        const float lx = proj[96] + 0.1f * proj[p * 2 + 0];
        const float ly = proj[97] + 0.1f * proj[p * 2 + 1];
        const float ix = ((lx + 1.f) * (float)Ww - 1.f) * 0.5f;
        const float iy = ((ly + 1.f) * (float)Hh - 1.f) * 0.5f;
        const float x0f = floorf(ix), y0f = floorf(iy);
        const int   x0  = (int)x0f,   y0  = (int)y0f;
        const float wx1 = ix - x0f, wx0 = 1.f - wx1;
        const float wy1 = iy - y0f, wy0 = 1.f - wy1;

        #pragma unroll
        for (int c = 0; c < 4; ++c) {
            const int   xc = x0 + (c & 1);
            const int   yc = y0 + (c >> 1);
            const float wx = (c & 1) ? wx1 : wx0;
            const float wy = (c >> 1) ? wy1 : wy0;
            const bool valid = (xc >= 0) && (xc < Ww) && (yc >= 0) && (yc < Hh);
            const int xi = min(max(xc, 0), Ww - 1);
            const int yi = min(max(yc, 0), Hh - 1);
            sW  [p * 4 + c] = valid ? (wx * wy * aw) : 0.f;
            sIdx[p * 4 + c] = (yi * Ww + xi) * (DIM / 4);   // float4 units
        }
    }
    __syncthreads();

    // ---- Phase 3: vectorized gather. cg = corner group (0..3), 32 corners each.
    // Each thread: float4 of channels [4*ch4 .. 4*ch4+3], 32 independent loads.
    const int cg  = tid >> 6;
    const int ch4 = tid & 63;
    const float4* __restrict__ Eb4 =
        (const float4*)(E + (size_t)b * (size_t)(Hh * Ww) * DIM);

    float4 acc = make_float4(0.f, 0.f, 0.f, 0.f);
    #pragma unroll
    for (int t = 0; t < 32; ++t) {
        const int   i   = cg * 32 + t;
        const float w   = sW[i];
        const int   idx = sIdx[i];
        const float4 e  = Eb4[(size_t)idx + ch4];
        acc.x = fmaf(w, e.x, acc.x);
        acc.y = fmaf(w, e.y, acc.y);
        acc.z = fmaf(w, e.z, acc.z);
        acc.w = fmaf(w, e.w, acc.w);
    }
    red[cg][ch4] = acc;
    __syncthreads();

    if (cg == 0) {
        const float4 r0 = red[0][ch4];
        const float4 r1 = red[1][ch4];
        const float4 r2 = red[2][ch4];
        const float4 r3 = red[3][ch4];
        float4 o;
        o.x = (r0.x + r1.x) + (r2.x + r3.x);
        o.y = (r0.y + r1.y) + (r2.y + r3.y);
        o.z = (r0.z + r1.z) + (r2.z + r3.z);
        o.w = (r0.w + r1.w) + (r2.w + r3.w);
        *(float4*)&agg[(size_t)row * DIM + ch4 * 4] = o;
    }
}

// ---------------------------------------------------------------------------
// Kernel B: out = agg @ Wp + bp.  [8192,256] x [256,256], fp32 vector FMA.
// 64x64 tile per block, BK=16, 256 threads, 4x4 micro-tile per thread.
// (unchanged this round — isolate the kernel A experiment)
// ---------------------------------------------------------------------------
__global__ __launch_bounds__(256) void proj_gemm_kernel(
    const float* __restrict__ A,      // [BM, 256]
    const float* __restrict__ Wp,     // [256, 256]
    const float* __restrict__ bp,     // [256]
    float* __restrict__ out)          // [BM, 256]
{
    __shared__ float As[16][64];      // transposed A tile: As[k][m]
    __shared__ float Bs[16][64];      // Bs[k][n]

    const int tid = threadIdx.x;
    const int mb  = blockIdx.x * 64;
    const int nb  = blockIdx.y * 64;
    const int tm  = (tid >> 4) << 2;  // row offset in tile
    const int tn  = (tid & 15) << 2;  // col offset in tile

    float acc[4][4] = {};

    for (int kb = 0; kb < DIM; kb += 16) {
        {
            const int m  = tid & 63;
            const int k0 = (tid >> 6) << 2;
            const float4 v = *(const float4*)&A[(size_t)(mb + m) * DIM + kb + k0];
            As[k0 + 0][m] = v.x; As[k0 + 1][m] = v.y;
            As[k0 + 2][m] = v.z; As[k0 + 3][m] = v.w;
            const int k = tid >> 4;
            const int n = (tid & 15) << 2;
            *(float4*)&Bs[k][n] = *(const float4*)&Wp[(size_t)(kb + k) * DIM + nb + n];
        }
        __syncthreads();

        #pragma unroll
        for (int k = 0; k < 16; ++k) {
            const float4 a  = *(const float4*)&As[k][tm];
            const float4 b4 = *(const float4*)&Bs[k][tn];
            acc[0][0] = fmaf(a.x, b4.x, acc[0][0]);
            acc[0][1] = fmaf(a.x, b4.y, acc[0][1]);
            acc[0][2] = fmaf(a.x, b4.z, acc[0][2]);
            acc[0][3] = fmaf(a.x, b4.w, acc[0][3]);
            acc[1][0] = fmaf(a.y, b4.x, acc[1][0]);
            acc[1][1] = fmaf(a.y, b4.y, acc[1][1]);
            acc[1][2] = fmaf(a.y, b4.z, acc[1][2]);
            acc[1][3] = fmaf(a.y, b4.w, acc[1][3]);
            acc[2][0] = fmaf(a.z, b4.x, acc[2][0]);
            acc[2][1] = fmaf(a.z, b4.y, acc[2][1]);
            acc[2][2] = fmaf(a.z, b4.z, acc[2][2]);
            acc[2][3] = fmaf(a.z, b4.w, acc[2][3]);
            acc[3][0] = fmaf(a.w, b4.x, acc[3][0]);
            acc[3][1] = fmaf(a.w, b4.y, acc[3][1]);
            acc[3][2] = fmaf(a.w, b4.z, acc[3][2]);
            acc[3][3] = fmaf(a.w, b4.w, acc[3][3]);
        }
        __syncthreads();
    }

    const float4 bv = *(const float4*)&bp[nb + tn];
    #pragma unroll
    for (int i = 0; i < 4; ++i) {
        float4 o;
        o.x = acc[i][0] + bv.x;
        o.y = acc[i][1] + bv.y;
        o.z = acc[i][2] + bv.z;
        o.w = acc[i][3] + bv.w;
        *(float4*)&out[(size_t)(mb + tm + i) * DIM + nb + tn] = o;
    }
}

// ---------------------------------------------------------------------------
extern "C" void kernel_launch(void* const* d_in, const int* in_sizes, int n_in,
                              void* d_out, int out_size, void* d_ws, size_t ws_size,
                              hipStream_t stream)
{
    const float* SADQ = (const float*)d_in[0];
    const float* E    = (const float*)d_in[1];
    const float* Wo   = (const float*)d_in[2];
    const float* bo   = (const float*)d_in[3];
    const float* Wa   = (const float*)d_in[4];
    const float* ba   = (const float*)d_in[5];
    const float* Wr   = (const float*)d_in[6];
    const float* br   = (const float*)d_in[7];
    const float* Wp   = (const float*)d_in[8];
    const float* bp   = (const float*)d_in[9];
    const int*   Hp   = (const int*)d_in[10];
    const int*   Wdp  = (const int*)d_in[11];

    float* agg = (float*)d_ws;                 // [B*M, D] fp32 = 8 MB
    float* out = (float*)d_out;

    const int BM = in_sizes[0] / DIM;          // 8192 rows

    fused_sample_kernel<<<BM, 256, 0, stream>>>(
        SADQ, E, Wo, bo, Wa, ba, Wr, br, Hp, Wdp, agg);

    dim3 g2(BM / 64, DIM / 64);
    proj_gemm_kernel<<<g2, 256, 0, stream>>>(agg, Wp, bp, out);
}

// Round 5
// 216.240 us; speedup vs baseline: 1.1551x; 1.0615x over previous
//
#include <hip/hip_runtime.h>
#include <hip/hip_bf16.h>
#include <math.h>

// Problem constants (fixed by setup_inputs: B=8, M=1024, D=256, H=W=100)
#define BATCH 8
#define MQ    1024
#define DIM   256
#define NHEAD 8
#define NPTS  4
#define NPROJ 98            // 64 offsets + 32 attn logits + 2 base-ref
#define NCORN (NHEAD * NPTS * 4)   // 128 corner samples per row

typedef __attribute__((ext_vector_type(8))) short  short8;  // 8 bf16 = 4 VGPR
typedef __attribute__((ext_vector_type(4))) float  f32x4;

static __device__ __forceinline__ ushort f2bf(float f) {
    union { float f; unsigned u; } v; v.f = f;
    const unsigned r = v.u + 0x7fffu + ((v.u >> 16) & 1u);   // round-nearest-even
    return (ushort)(r >> 16);
}

// ---------------------------------------------------------------------------
// Kernel A: fused projections + softmax + bilinear sample + weighted agg.
// One block per (b, m) row. 256 threads = 4 corner-groups x 64 float4 lanes.
// Epilogue now writes agg as bf16 (feeds the MFMA GEMM).
// ---------------------------------------------------------------------------
__global__ __launch_bounds__(256) void fused_sample_kernel(
    const float* __restrict__ SADQ,   // [B, M, D]
    const float* __restrict__ E,      // [B, H*W, D]
    const float* __restrict__ Wo, const float* __restrict__ bo,   // [D,64],[64]
    const float* __restrict__ Wa, const float* __restrict__ ba,   // [D,32],[32]
    const float* __restrict__ Wr, const float* __restrict__ br,   // [D,2],[2]
    const int*   __restrict__ Hp, const int* __restrict__ Wdp,    // scalars
    ushort* __restrict__ aggb)        // [B*M, D] bf16
{
    const int row = blockIdx.x;       // b*MQ + m
    const int b   = row / MQ;
    const int tid = threadIdx.x;

    __shared__ float  qs[DIM];
    __shared__ float  proj[128];      // [0,64) offsets, [64,96) logits, [96,98) base
    __shared__ float  partial[128];   // upper-half d partial sums
    __shared__ float  sW[NCORN];
    __shared__ int    sIdx[NCORN];    // pixel index in float4 units (pix*64)
    __shared__ float4 red[4][64];     // cross-corner-group reduction

    qs[tid] = SADQ[(size_t)row * DIM + tid];
    __syncthreads();

    // ---- Phase 1: projections. Output j computed by two threads (d halves).
    {
        const int j    = tid & 127;
        const int half = tid >> 7;
        float s = 0.f, bias = 0.f;
        if (j < NPROJ) {
            const float* Wb; int col, ncols;
            if (j < 64)      { Wb = Wo; col = j;      ncols = 64; bias = bo[col]; }
            else if (j < 96) { Wb = Wa; col = j - 64; ncols = 32; bias = ba[col]; }
            else             { Wb = Wr; col = j - 96; ncols = 2;  bias = br[col]; }
            const float* wp = Wb + (size_t)(half * 128) * ncols + col;
            const float* qp = qs + half * 128;
            #pragma unroll 8
            for (int d = 0; d < 128; ++d)
                s = fmaf(qp[d], wp[(size_t)d * ncols], s);
        }
        if (half) partial[j] = s;
        __syncthreads();
        if (!half && j < NPROJ) proj[j] = s + bias + partial[j];
        __syncthreads();
    }

    // ---- Phase 2: softmax over each head's 4 points + per-point corner setup.
    const int Hh = *Hp;
    const int Ww = *Wdp;
    if (tid < NHEAD * NPTS) {
        const int p = tid;            // linear (h*4 + pt)
        const int h = p >> 2;
        const float l0 = proj[64 + h * 4 + 0];
        const float l1 = proj[64 + h * 4 + 1];
        const float l2 = proj[64 + h * 4 + 2];
        const float l3 = proj[64 + h * 4 + 3];
        const float mx = fmaxf(fmaxf(l0, l1), fmaxf(l2, l3));
        const float e0 = expf(l0 - mx), e1 = expf(l1 - mx),
                    e2 = expf(l2 - mx), e3 = expf(l3 - mx);
        const float inv = 1.f / (e0 + e1 + e2 + e3);
        const float aw  = expf(proj[64 + p] - mx) * inv * (1.f / NHEAD);

        const float lx = proj[96] + 0.1f * proj[p * 2 + 0];
        const float ly = proj[97] + 0.1f * proj[p * 2 + 1];
        const float ix = ((lx + 1.f) * (float)Ww - 1.f) * 0.5f;
        const float iy = ((ly + 1.f) * (float)Hh - 1.f) * 0.5f;
        const float x0f = floorf(ix), y0f = floorf(iy);
        const int   x0  = (int)x0f,   y0  = (int)y0f;
        const float wx1 = ix - x0f, wx0 = 1.f - wx1;
        const float wy1 = iy - y0f, wy0 = 1.f - wy1;

        #pragma unroll
        for (int c = 0; c < 4; ++c) {
            const int   xc = x0 + (c & 1);
            const int   yc = y0 + (c >> 1);
            const float wx = (c & 1) ? wx1 : wx0;
            const float wy = (c >> 1) ? wy1 : wy0;
            const bool valid = (xc >= 0) && (xc < Ww) && (yc >= 0) && (yc < Hh);
            const int xi = min(max(xc, 0), Ww - 1);
            const int yi = min(max(yc, 0), Hh - 1);
            sW  [p * 4 + c] = valid ? (wx * wy * aw) : 0.f;
            sIdx[p * 4 + c] = (yi * Ww + xi) * (DIM / 4);   // float4 units
        }
    }
    __syncthreads();

    // ---- Phase 3: vectorized gather. cg = corner group (0..3), 32 corners each.
    const int cg  = tid >> 6;
    const int ch4 = tid & 63;
    const float4* __restrict__ Eb4 =
        (const float4*)(E + (size_t)b * (size_t)(Hh * Ww) * DIM);

    float4 acc = make_float4(0.f, 0.f, 0.f, 0.f);
    #pragma unroll
    for (int t = 0; t < 32; ++t) {
        const int   i   = cg * 32 + t;
        const float w   = sW[i];
        const int   idx = sIdx[i];
        const float4 e  = Eb4[(size_t)idx + ch4];
        acc.x = fmaf(w, e.x, acc.x);
        acc.y = fmaf(w, e.y, acc.y);
        acc.z = fmaf(w, e.z, acc.z);
        acc.w = fmaf(w, e.w, acc.w);
    }
    red[cg][ch4] = acc;
    __syncthreads();

    if (cg == 0) {
        const float4 r0 = red[0][ch4];
        const float4 r1 = red[1][ch4];
        const float4 r2 = red[2][ch4];
        const float4 r3 = red[3][ch4];
        ushort4 o;
        o.x = f2bf((r0.x + r1.x) + (r2.x + r3.x));
        o.y = f2bf((r0.y + r1.y) + (r2.y + r3.y));
        o.z = f2bf((r0.z + r1.z) + (r2.z + r3.z));
        o.w = f2bf((r0.w + r1.w) + (r2.w + r3.w));
        *(ushort4*)&aggb[(size_t)row * DIM + ch4 * 4] = o;
    }
}

// ---------------------------------------------------------------------------
// Tiny kernel: WpT[n][k] = bf16(Wp[k][n]).  256 blocks x 256 threads.
// ---------------------------------------------------------------------------
__global__ __launch_bounds__(256) void wp_convert_kernel(
    const float* __restrict__ Wp, ushort* __restrict__ WpT)
{
    const int k = blockIdx.x;
    const int n = threadIdx.x;
    WpT[(size_t)n * DIM + k] = f2bf(Wp[(size_t)k * DIM + n]);
}

// ---------------------------------------------------------------------------
// Kernel B: out = agg @ Wp + bp via bf16 MFMA (fp32 accumulate).
// 64x64 tile / block, 4 waves in 2x2, each wave 32x32 (2x2 16x16 frags), BK=32.
// A = aggb [M][256] bf16 row-major; BT = WpT [n][k] bf16 so both operand
// fragments are contiguous-k ds_read_b128 reads. LDS pitch 40 bf16 (80 B)
// -> max 2-way bank aliasing (free per m136).
// Verified layouts (learn_hip m89/m91): A row=lane&15, k=(lane>>4)*8+j;
// B col=lane&15, k same; D col=lane&15, row=(lane>>4)*4+reg.
// ---------------------------------------------------------------------------
__global__ __launch_bounds__(256) void mfma_gemm_kernel(
    const ushort* __restrict__ A,     // [M, 256] bf16
    const ushort* __restrict__ BT,    // [256, 256] bf16 (transposed Wp)
    const float*  __restrict__ bp,    // [256]
    float* __restrict__ out)          // [M, 256]
{
    __shared__ ushort ldsA[64 * 40];
    __shared__ ushort ldsB[64 * 40];

    const int tid  = threadIdx.x;
    const int mb   = blockIdx.x * 64;
    const int nb   = blockIdx.y * 64;
    const int wave = tid >> 6;
    const int lane = tid & 63;
    const int r0   = (wave >> 1) * 32;    // wave row offset in tile
    const int c0   = (wave & 1) * 32;     // wave col offset in tile
    const int lrow = lane & 15;
    const int kgrp = lane >> 4;

    const int sm = tid >> 2;              // staging row 0..63
    const int sc = (tid & 3) * 8;         // staging k-chunk (8 bf16 = 16 B)

    f32x4 acc00 = {0.f, 0.f, 0.f, 0.f};
    f32x4 acc01 = {0.f, 0.f, 0.f, 0.f};
    f32x4 acc10 = {0.f, 0.f, 0.f, 0.f};
    f32x4 acc11 = {0.f, 0.f, 0.f, 0.f};

    for (int kb = 0; kb < DIM; kb += 32) {
        *(uint4*)&ldsA[sm * 40 + sc] =
            *(const uint4*)&A[(size_t)(mb + sm) * DIM + kb + sc];
        *(uint4*)&ldsB[sm * 40 + sc] =
            *(const uint4*)&BT[(size_t)(nb + sm) * DIM + kb + sc];
        __syncthreads();

        const short8 a0 = *(const short8*)&ldsA[(r0 + lrow)      * 40 + kgrp * 8];
        const short8 a1 = *(const short8*)&ldsA[(r0 + 16 + lrow) * 40 + kgrp * 8];
        const short8 b0 = *(const short8*)&ldsB[(c0 + lrow)      * 40 + kgrp * 8];
        const short8 b1 = *(const short8*)&ldsB[(c0 + 16 + lrow) * 40 + kgrp * 8];

        acc00 = __builtin_amdgcn_mfma_f32_16x16x32_bf16(a0, b0, acc00, 0, 0, 0);
        acc01 = __builtin_amdgcn_mfma_f32_16x16x32_bf16(a0, b1, acc01, 0, 0, 0);
        acc10 = __builtin_amdgcn_mfma_f32_16x16x32_bf16(a1, b0, acc10, 0, 0, 0);
        acc11 = __builtin_amdgcn_mfma_f32_16x16x32_bf16(a1, b1, acc11, 0, 0, 0);
        __syncthreads();
    }

    // Epilogue: D col=lane&15, row=(lane>>4)*4+reg.
    const int orow = mb + r0 + kgrp * 4;
    const int ocol = nb + c0 + lrow;
    const float bp0 = bp[ocol];
    const float bp1 = bp[ocol + 16];
    #pragma unroll
    for (int reg = 0; reg < 4; ++reg) {
        out[(size_t)(orow + reg)      * DIM + ocol]      = acc00[reg] + bp0;
        out[(size_t)(orow + reg)      * DIM + ocol + 16] = acc01[reg] + bp1;
        out[(size_t)(orow + 16 + reg) * DIM + ocol]      = acc10[reg] + bp0;
        out[(size_t)(orow + 16 + reg) * DIM + ocol + 16] = acc11[reg] + bp1;
    }
}

// ---------------------------------------------------------------------------
extern "C" void kernel_launch(void* const* d_in, const int* in_sizes, int n_in,
                              void* d_out, int out_size, void* d_ws, size_t ws_size,
                              hipStream_t stream)
{
    const float* SADQ = (const float*)d_in[0];
    const float* E    = (const float*)d_in[1];
    const float* Wo   = (const float*)d_in[2];
    const float* bo   = (const float*)d_in[3];
    const float* Wa   = (const float*)d_in[4];
    const float* ba   = (const float*)d_in[5];
    const float* Wr   = (const float*)d_in[6];
    const float* br   = (const float*)d_in[7];
    const float* Wp   = (const float*)d_in[8];
    const float* bp   = (const float*)d_in[9];
    const int*   Hp   = (const int*)d_in[10];
    const int*   Wdp  = (const int*)d_in[11];

    const int BM = in_sizes[0] / DIM;          // 8192 rows

    ushort* aggb = (ushort*)d_ws;                              // 4 MB bf16 agg
    ushort* WpT  = (ushort*)((char*)d_ws + (size_t)BM * DIM * 2); // 128 KB
    float*  out  = (float*)d_out;

    fused_sample_kernel<<<BM, 256, 0, stream>>>(
        SADQ, E, Wo, bo, Wa, ba, Wr, br, Hp, Wdp, aggb);

    wp_convert_kernel<<<DIM, 256, 0, stream>>>(Wp, WpT);

    dim3 g2(BM / 64, DIM / 64);
    mfma_gemm_kernel<<<g2, 256, 0, stream>>>(aggb, WpT, bp, out);
}

// Round 6
// 215.934 us; speedup vs baseline: 1.1567x; 1.0014x over previous
//
#include <hip/hip_runtime.h>
#include <hip/hip_bf16.h>
#include <math.h>

// Problem constants (fixed by setup_inputs: B=8, M=1024, D=256, H=W=100)
#define BATCH 8
#define MQ    1024
#define DIM   256
#define NHEAD 8
#define NPTS  4
#define NPROJ 98            // 64 offsets + 32 attn logits + 2 base-ref
#define NCORN (NHEAD * NPTS * 4)   // 128 corner samples per row

typedef __attribute__((ext_vector_type(8))) short  short8;  // 8 bf16 = 4 VGPR
typedef __attribute__((ext_vector_type(4))) float  f32x4;

static __device__ __forceinline__ ushort f2bf(float f) {
    union { float f; unsigned u; } v; v.f = f;
    const unsigned r = v.u + 0x7fffu + ((v.u >> 16) & 1u);   // round-nearest-even
    return (ushort)(r >> 16);
}

// ---------------------------------------------------------------------------
// Kernel A: fused projections + softmax + bilinear sample + weighted agg.
// One block per (b, m) row. 256 threads = 4 corner-groups x 64 float4 lanes.
// Phase 3: explicit 8-deep load batching to force MLP (VGPR budget ~80).
// ---------------------------------------------------------------------------
__global__ __launch_bounds__(256) void fused_sample_kernel(
    const float* __restrict__ SADQ,   // [B, M, D]
    const float* __restrict__ E,      // [B, H*W, D]
    const float* __restrict__ Wo, const float* __restrict__ bo,   // [D,64],[64]
    const float* __restrict__ Wa, const float* __restrict__ ba,   // [D,32],[32]
    const float* __restrict__ Wr, const float* __restrict__ br,   // [D,2],[2]
    const int*   __restrict__ Hp, const int* __restrict__ Wdp,    // scalars
    ushort* __restrict__ aggb)        // [B*M, D] bf16
{
    const int row = blockIdx.x;       // b*MQ + m
    const int b   = row / MQ;
    const int tid = threadIdx.x;

    __shared__ float  qs[DIM];
    __shared__ float  proj[128];      // [0,64) offsets, [64,96) logits, [96,98) base
    __shared__ float  partial[128];   // upper-half d partial sums
    __shared__ float  sW[NCORN];
    __shared__ int    sIdx[NCORN];    // pixel index in float4 units (pix*64)
    __shared__ float4 red[4][64];     // cross-corner-group reduction

    qs[tid] = SADQ[(size_t)row * DIM + tid];
    __syncthreads();

    // ---- Phase 1: projections. Output j computed by two threads (d halves).
    {
        const int j    = tid & 127;
        const int half = tid >> 7;
        float s = 0.f, bias = 0.f;
        if (j < NPROJ) {
            const float* Wb; int col, ncols;
            if (j < 64)      { Wb = Wo; col = j;      ncols = 64; bias = bo[col]; }
            else if (j < 96) { Wb = Wa; col = j - 64; ncols = 32; bias = ba[col]; }
            else             { Wb = Wr; col = j - 96; ncols = 2;  bias = br[col]; }
            const float* wp = Wb + (size_t)(half * 128) * ncols + col;
            const float* qp = qs + half * 128;
            #pragma unroll 8
            for (int d = 0; d < 128; ++d)
                s = fmaf(qp[d], wp[(size_t)d * ncols], s);
        }
        if (half) partial[j] = s;
        __syncthreads();
        if (!half && j < NPROJ) proj[j] = s + bias + partial[j];
        __syncthreads();
    }

    // ---- Phase 2: softmax over each head's 4 points + per-point corner setup.
    const int Hh = *Hp;
    const int Ww = *Wdp;
    if (tid < NHEAD * NPTS) {
        const int p = tid;            // linear (h*4 + pt)
        const int h = p >> 2;
        const float l0 = proj[64 + h * 4 + 0];
        const float l1 = proj[64 + h * 4 + 1];
        const float l2 = proj[64 + h * 4 + 2];
        const float l3 = proj[64 + h * 4 + 3];
        const float mx = fmaxf(fmaxf(l0, l1), fmaxf(l2, l3));
        const float e0 = expf(l0 - mx), e1 = expf(l1 - mx),
                    e2 = expf(l2 - mx), e3 = expf(l3 - mx);
        const float inv = 1.f / (e0 + e1 + e2 + e3);
        const float aw  = expf(proj[64 + p] - mx) * inv * (1.f / NHEAD);

        const float lx = proj[96] + 0.1f * proj[p * 2 + 0];
        const float ly = proj[97] + 0.1f * proj[p * 2 + 1];
        const float ix = ((lx + 1.f) * (float)Ww - 1.f) * 0.5f;
        const float iy = ((ly + 1.f) * (float)Hh - 1.f) * 0.5f;
        const float x0f = floorf(ix), y0f = floorf(iy);
        const int   x0  = (int)x0f,   y0  = (int)y0f;
        const float wx1 = ix - x0f, wx0 = 1.f - wx1;
        const float wy1 = iy - y0f, wy0 = 1.f - wy1;

        #pragma unroll
        for (int c = 0; c < 4; ++c) {
            const int   xc = x0 + (c & 1);
            const int   yc = y0 + (c >> 1);
            const float wx = (c & 1) ? wx1 : wx0;
            const float wy = (c >> 1) ? wy1 : wy0;
            const bool valid = (xc >= 0) && (xc < Ww) && (yc >= 0) && (yc < Hh);
            const int xi = min(max(xc, 0), Ww - 1);
            const int yi = min(max(yc, 0), Hh - 1);
            sW  [p * 4 + c] = valid ? (wx * wy * aw) : 0.f;
            sIdx[p * 4 + c] = (yi * Ww + xi) * (DIM / 4);   // float4 units
        }
    }
    __syncthreads();

    // ---- Phase 3: gather with explicit 8-deep load batches (forced MLP).
    const int cg  = tid >> 6;
    const int ch4 = tid & 63;
    const float4* __restrict__ Eb4 =
        (const float4*)(E + (size_t)b * (size_t)(Hh * Ww) * DIM);

    float4 acc = make_float4(0.f, 0.f, 0.f, 0.f);
    #pragma unroll
    for (int tt = 0; tt < 32; tt += 8) {
        float w[8]; int id[8];
        #pragma unroll
        for (int j = 0; j < 8; ++j) {
            w[j]  = sW[cg * 32 + tt + j];
            id[j] = sIdx[cg * 32 + tt + j];
        }
        float4 e[8];
        #pragma unroll
        for (int j = 0; j < 8; ++j)
            e[j] = Eb4[(size_t)id[j] + ch4];     // 8 independent loads in flight
        #pragma unroll
        for (int j = 0; j < 8; ++j) {
            acc.x = fmaf(w[j], e[j].x, acc.x);
            acc.y = fmaf(w[j], e[j].y, acc.y);
            acc.z = fmaf(w[j], e[j].z, acc.z);
            acc.w = fmaf(w[j], e[j].w, acc.w);
        }
    }
    red[cg][ch4] = acc;
    __syncthreads();

    if (cg == 0) {
        const float4 r0 = red[0][ch4];
        const float4 r1 = red[1][ch4];
        const float4 r2 = red[2][ch4];
        const float4 r3 = red[3][ch4];
        ushort4 o;
        o.x = f2bf((r0.x + r1.x) + (r2.x + r3.x));
        o.y = f2bf((r0.y + r1.y) + (r2.y + r3.y));
        o.z = f2bf((r0.z + r1.z) + (r2.z + r3.z));
        o.w = f2bf((r0.w + r1.w) + (r2.w + r3.w));
        *(ushort4*)&aggb[(size_t)row * DIM + ch4 * 4] = o;
    }
}

// ---------------------------------------------------------------------------
// Tiny kernel: WpT[n][k] = bf16(Wp[k][n]).  (unchanged)
// ---------------------------------------------------------------------------
__global__ __launch_bounds__(256) void wp_convert_kernel(
    const float* __restrict__ Wp, ushort* __restrict__ WpT)
{
    const int k = blockIdx.x;
    const int n = threadIdx.x;
    WpT[(size_t)n * DIM + k] = f2bf(Wp[(size_t)k * DIM + n]);
}

// ---------------------------------------------------------------------------
// Kernel B: out = agg @ Wp + bp via bf16 MFMA (fp32 accumulate). (unchanged)
// ---------------------------------------------------------------------------
__global__ __launch_bounds__(256) void mfma_gemm_kernel(
    const ushort* __restrict__ A,     // [M, 256] bf16
    const ushort* __restrict__ BT,    // [256, 256] bf16 (transposed Wp)
    const float*  __restrict__ bp,    // [256]
    float* __restrict__ out)          // [M, 256]
{
    __shared__ ushort ldsA[64 * 40];
    __shared__ ushort ldsB[64 * 40];

    const int tid  = threadIdx.x;
    const int mb   = blockIdx.x * 64;
    const int nb   = blockIdx.y * 64;
    const int wave = tid >> 6;
    const int lane = tid & 63;
    const int r0   = (wave >> 1) * 32;
    const int c0   = (wave & 1) * 32;
    const int lrow = lane & 15;
    const int kgrp = lane >> 4;

    const int sm = tid >> 2;
    const int sc = (tid & 3) * 8;

    f32x4 acc00 = {0.f, 0.f, 0.f, 0.f};
    f32x4 acc01 = {0.f, 0.f, 0.f, 0.f};
    f32x4 acc10 = {0.f, 0.f, 0.f, 0.f};
    f32x4 acc11 = {0.f, 0.f, 0.f, 0.f};

    for (int kb = 0; kb < DIM; kb += 32) {
        *(uint4*)&ldsA[sm * 40 + sc] =
            *(const uint4*)&A[(size_t)(mb + sm) * DIM + kb + sc];
        *(uint4*)&ldsB[sm * 40 + sc] =
            *(const uint4*)&BT[(size_t)(nb + sm) * DIM + kb + sc];
        __syncthreads();

        const short8 a0 = *(const short8*)&ldsA[(r0 + lrow)      * 40 + kgrp * 8];
        const short8 a1 = *(const short8*)&ldsA[(r0 + 16 + lrow) * 40 + kgrp * 8];
        const short8 b0 = *(const short8*)&ldsB[(c0 + lrow)      * 40 + kgrp * 8];
        const short8 b1 = *(const short8*)&ldsB[(c0 + 16 + lrow) * 40 + kgrp * 8];

        acc00 = __builtin_amdgcn_mfma_f32_16x16x32_bf16(a0, b0, acc00, 0, 0, 0);
        acc01 = __builtin_amdgcn_mfma_f32_16x16x32_bf16(a0, b1, acc01, 0, 0, 0);
        acc10 = __builtin_amdgcn_mfma_f32_16x16x32_bf16(a1, b0, acc10, 0, 0, 0);
        acc11 = __builtin_amdgcn_mfma_f32_16x16x32_bf16(a1, b1, acc11, 0, 0, 0);
        __syncthreads();
    }

    const int orow = mb + r0 + kgrp * 4;
    const int ocol = nb + c0 + lrow;
    const float bp0 = bp[ocol];
    const float bp1 = bp[ocol + 16];
    #pragma unroll
    for (int reg = 0; reg < 4; ++reg) {
        out[(size_t)(orow + reg)      * DIM + ocol]      = acc00[reg] + bp0;
        out[(size_t)(orow + reg)      * DIM + ocol + 16] = acc01[reg] + bp1;
        out[(size_t)(orow + 16 + reg) * DIM + ocol]      = acc10[reg] + bp0;
        out[(size_t)(orow + 16 + reg) * DIM + ocol + 16] = acc11[reg] + bp1;
    }
}

// ---------------------------------------------------------------------------
extern "C" void kernel_launch(void* const* d_in, const int* in_sizes, int n_in,
                              void* d_out, int out_size, void* d_ws, size_t ws_size,
                              hipStream_t stream)
{
    const float* SADQ = (const float*)d_in[0];
    const float* E    = (const float*)d_in[1];
    const float* Wo   = (const float*)d_in[2];
    const float* bo   = (const float*)d_in[3];
    const float* Wa   = (const float*)d_in[4];
    const float* ba   = (const float*)d_in[5];
    const float* Wr   = (const float*)d_in[6];
    const float* br   = (const float*)d_in[7];
    const float* Wp   = (const float*)d_in[8];
    const float* bp   = (const float*)d_in[9];
    const int*   Hp   = (const int*)d_in[10];
    const int*   Wdp  = (const int*)d_in[11];

    const int BM = in_sizes[0] / DIM;          // 8192 rows

    ushort* aggb = (ushort*)d_ws;                                 // 4 MB bf16
    ushort* WpT  = (ushort*)((char*)d_ws + (size_t)BM * DIM * 2); // 128 KB
    float*  out  = (float*)d_out;

    fused_sample_kernel<<<BM, 256, 0, stream>>>(
        SADQ, E, Wo, bo, Wa, ba, Wr, br, Hp, Wdp, aggb);

    wp_convert_kernel<<<DIM, 256, 0, stream>>>(Wp, WpT);

    dim3 g2(BM / 64, DIM / 64);
    mfma_gemm_kernel<<<g2, 256, 0, stream>>>(aggb, WpT, bp, out);
}